// Round 4
// baseline (146.266 us; speedup 1.0000x reference)
//
#include <hip/hip_runtime.h>
#include <math.h>

#define KNOTS 8
#define HIDN 32
#define TT 4096
#define CC 512
#define NB 32
#define BOUNDF 5.0f
#define CT 32          // channels per block
#define NTG 32         // t-groups (threads striding over T)
#define TPT (TT / NTG) // 128 elements per thread

// One block = one (batch, 32-channel) slice, 1024 threads.
// Phase 1: moments over T. Finalize: 32 lanes -> spline params in LDS.
// Phase 2: re-read own 0.5 MB slice in REVERSE t order (L3-hot), apply spline.
__global__ __launch_bounds__(1024, 8)
void k_fused(const float* __restrict__ x, const float* __restrict__ W1,
             const float* __restrict__ b1, const float* __restrict__ W2,
             const float* __restrict__ b2, float* __restrict__ out)
{
    const int bb = blockIdx.y;               // 0..31
    const int c0 = blockIdx.x * CT;          // 0,32,...,480
    const int ci = threadIdx.x & (CT - 1);   // 0..31
    const int tg = threadIdx.x >> 5;         // 0..31

    __shared__ float red[NTG][4][CT];
    __shared__ float mom[4][CT];
    __shared__ float pA[CT], pB[CT];
    __shared__ float pKx[7][CT];
    __shared__ float4 binsA[KNOTS][CT];      // (kx_l, 1/w, ky_l, h*s)
    __shared__ float4 binsB[KNOTS][CT];      // (h*d0, d1+d0-2s, s, 0)

    const size_t base = (size_t)bb * TT * CC + c0 + ci;
    const float* pxt = x + base + (size_t)tg * CC;

    // ---- Phase 1: raw moments (each thread: 128 elements, stride 32 in t) ----
    float s1 = 0.f, s2 = 0.f, s3 = 0.f, s4 = 0.f;
    #pragma unroll 8
    for (int k = 0; k < TPT; ++k) {
        float v  = pxt[(size_t)k * (NTG * CC)];
        float v2 = v * v;
        s1 += v;
        s2 = fmaf(v,  v,  s2);
        s3 = fmaf(v2, v,  s3);
        s4 = fmaf(v2, v2, s4);
    }
    red[tg][0][ci] = s1; red[tg][1][ci] = s2;
    red[tg][2][ci] = s3; red[tg][3][ci] = s4;
    __syncthreads();

    if (threadIdx.x < 4 * CT) {
        const int m = threadIdx.x >> 5, c = threadIdx.x & (CT - 1);
        float acc = 0.f;
        #pragma unroll
        for (int g = 0; g < NTG; ++g) acc += red[g][m][c];
        mom[m][c] = acc;
    }
    __syncthreads();

    // ---- Finalize: one lane per channel row ----
    if (threadIdx.x < CT) {
        const int c = threadIdx.x;
        const float n  = (float)TT;
        const float t1 = mom[0][c], t2 = mom[1][c], t3 = mom[2][c], t4 = mom[3][c];
        const float mu  = t1 / n;
        const float ex2 = t2 / n, ex3 = t3 / n, ex4 = t4 / n;
        float var = (t2 - n * mu * mu) / (n - 1.f);
        var = fmaxf(var, 0.f);
        const float sig  = fmaxf(sqrtf(var), 1e-4f);
        const float inv  = 1.f / sig;
        const float mu2  = mu * mu;
        const float ez3  = ex3 - 3.f * mu * ex2 + 2.f * mu * mu2;
        const float ez4  = ex4 - 4.f * mu * ex3 + 6.f * mu2 * ex2 - 3.f * mu2 * mu2;
        const float inv2 = inv * inv;
        const float skew  = ez3 * inv2 * inv;
        const float ekurt = ez4 * inv2 * inv2 - 3.f;

        float hid[HIDN];
        #pragma unroll
        for (int h = 0; h < HIDN; ++h) {
            float v = fmaf(W1[2*h], skew, fmaf(W1[2*h+1], ekurt, b1[h]));
            hid[h] = fmaxf(v, 0.f);
        }

        float e[KNOTS], kxr[KNOTS+1], kyr[KNOTS+1], dr[KNOTS+1];
        {   // widths -> kx
            float mx = -1e30f;
            #pragma unroll
            for (int o = 0; o < KNOTS; ++o) {
                float acc = b2[o];
                #pragma unroll
                for (int h = 0; h < HIDN; ++h) acc = fmaf(W2[o*HIDN + h], hid[h], acc);
                e[o] = acc; mx = fmaxf(mx, acc);
            }
            float sum = 0.f;
            #pragma unroll
            for (int o = 0; o < KNOTS; ++o) { e[o] = expf(e[o] - mx); sum += e[o]; }
            const float scale = (2.f * BOUNDF) / sum;
            float cum = -BOUNDF; kxr[0] = -BOUNDF;
            #pragma unroll
            for (int o = 0; o < KNOTS; ++o) { cum = fmaf(e[o], scale, cum); kxr[o+1] = cum; }
        }
        {   // heights -> ky
            float mx = -1e30f;
            #pragma unroll
            for (int o = 0; o < KNOTS; ++o) {
                float acc = b2[KNOTS + o];
                #pragma unroll
                for (int h = 0; h < HIDN; ++h) acc = fmaf(W2[(KNOTS+o)*HIDN + h], hid[h], acc);
                e[o] = acc; mx = fmaxf(mx, acc);
            }
            float sum = 0.f;
            #pragma unroll
            for (int o = 0; o < KNOTS; ++o) { e[o] = expf(e[o] - mx); sum += e[o]; }
            const float scale = (2.f * BOUNDF) / sum;
            float cum = -BOUNDF; kyr[0] = -BOUNDF;
            #pragma unroll
            for (int o = 0; o < KNOTS; ++o) { cum = fmaf(e[o], scale, cum); kyr[o+1] = cum; }
        }
        #pragma unroll
        for (int o = 0; o < KNOTS+1; ++o) {  // derivs = softplus + 1e-3
            float acc = b2[2*KNOTS + o];
            #pragma unroll
            for (int h = 0; h < HIDN; ++h) acc = fmaf(W2[(2*KNOTS+o)*HIDN + h], hid[h], acc);
            float sp = fmaxf(acc, 0.f) + log1pf(expf(-fabsf(acc)));
            dr[o] = sp + 1e-3f;
        }

        pA[c] = inv;
        pB[c] = -mu * inv;
        #pragma unroll
        for (int j = 1; j <= 7; ++j) pKx[j-1][c] = kxr[j];
        #pragma unroll
        for (int j = 0; j < KNOTS; ++j) {
            const float w  = kxr[j+1] - kxr[j];
            const float wm = fmaxf(w, 1e-8f);
            const float h  = kyr[j+1] - kyr[j];
            const float s  = h / wm;
            float4 A, Bq;
            A.x = kxr[j];  A.y = 1.f / wm;  A.z = kyr[j];  A.w = h * s;
            Bq.x = h * dr[j];  Bq.y = dr[j+1] + dr[j] - 2.f * s;  Bq.z = s;  Bq.w = 0.f;
            binsA[j][c] = A;
            binsB[j][c] = Bq;
        }
    }
    __syncthreads();

    // ---- Phase 2: re-read slice in REVERSE t order, apply spline ----
    const float a  = pA[ci];
    const float bz = pB[ci];
    const float kx1 = pKx[0][ci], kx2 = pKx[1][ci], kx3 = pKx[2][ci],
                kx4 = pKx[3][ci], kx5 = pKx[4][ci], kx6 = pKx[5][ci],
                kx7 = pKx[6][ci];
    float* pot = out + base + (size_t)tg * CC;

    for (int kb = TPT / 8 - 1; kb >= 0; --kb) {   // 15..0 (reverse)
        float xv[8];
        #pragma unroll
        for (int j = 0; j < 8; ++j)
            xv[j] = pxt[(size_t)(kb * 8 + j) * (NTG * CC)];
        #pragma unroll
        for (int j = 0; j < 8; ++j) {
            const float z = fmaf(xv[j], a, bz);
            const int idx = (z >= kx1) + (z >= kx2) + (z >= kx3) + (z >= kx4)
                          + (z >= kx5) + (z >= kx6) + (z >= kx7);
            const float4 A  = binsA[idx][ci];
            const float4 Bq = binsB[idx][ci];
            float zeta = (z - A.x) * A.y;
            zeta = fminf(fmaxf(zeta, 0.f), 1.f);
            const float u     = zeta - zeta * zeta;
            const float numer = fmaf(A.w * zeta, zeta, Bq.x * u);
            const float denom = fmaf(Bq.y, u, Bq.z);
            const float res   = fmaf(numer, __builtin_amdgcn_rcpf(fmaxf(denom, 1e-8f)), A.z);
            const float o = (fabsf(z) > BOUNDF) ? z : res;
            __builtin_nontemporal_store(o, &pot[(size_t)(kb * 8 + j) * (NTG * CC)]);
        }
    }
}

extern "C" void kernel_launch(void* const* d_in, const int* in_sizes, int n_in,
                              void* d_out, int out_size, void* d_ws, size_t ws_size,
                              hipStream_t stream) {
    const float* x  = (const float*)d_in[0];
    const float* W1 = (const float*)d_in[1];
    const float* b1 = (const float*)d_in[2];
    const float* W2 = (const float*)d_in[3];
    const float* b2 = (const float*)d_in[4];
    float* out = (float*)d_out;

    k_fused<<<dim3(CC / CT, NB), dim3(1024), 0, stream>>>(x, W1, b1, W2, b2, out);
}

// Round 5
// 129.107 us; speedup vs baseline: 1.1329x; 1.1329x over previous
//
#include <hip/hip_runtime.h>
#include <math.h>

#define KNOTS 8
#define HIDN 32
#define TT 4096
#define CC 512
#define NB 32
#define BOUNDF 5.0f
#define CT 32          // channels per block
#define NTG 16         // t-groups (threads striding over T)
#define TPT (TT / NTG) // 256 elements per thread

typedef _Float16 f16x2 __attribute__((ext_vector_type(2)));
union F32H { float f; f16x2 h; };

// One block = one (batch, 32-channel) slice, 512 threads.
// Phase 1: moments over T. Finalize: 32 lanes -> spline params in LDS
//          (ONE 16B record per bin: f32 -kxl*invw, f32 invw, f16 ky_l,h, f16 d0,d0+d1).
// Phase 2: re-read own 0.5 MB slice in REVERSE t order (L3-hot), apply spline,
//          nontemporal stores.
__global__ __launch_bounds__(512, 4)
void k_fused(const float* __restrict__ x, const float* __restrict__ W1,
             const float* __restrict__ b1, const float* __restrict__ W2,
             const float* __restrict__ b2, float* __restrict__ out)
{
    const int bb = blockIdx.y;               // 0..31
    const int c0 = blockIdx.x * CT;          // 0,32,...,480
    const int ci = threadIdx.x & (CT - 1);   // 0..31
    const int tg = threadIdx.x >> 5;         // 0..15

    __shared__ float red[NTG][4][CT];
    __shared__ float mom[4][CT];
    __shared__ float pA[CT], pB[CT];
    __shared__ float pKx[7][CT];
    __shared__ float4 bins[KNOTS * CT];      // packed bin records

    const size_t base = (size_t)bb * TT * CC + c0 + ci;
    const float* pxt = x + base + (size_t)tg * CC;

    // ---- Phase 1: raw moments (each thread: 256 elements, stride 16 in t) ----
    float s1 = 0.f, s2 = 0.f, s3 = 0.f, s4 = 0.f;
    #pragma unroll 8
    for (int k = 0; k < TPT; ++k) {
        float v  = pxt[(size_t)k * (NTG * CC)];
        float v2 = v * v;
        s1 += v;
        s2 = fmaf(v,  v,  s2);
        s3 = fmaf(v2, v,  s3);
        s4 = fmaf(v2, v2, s4);
    }
    red[tg][0][ci] = s1; red[tg][1][ci] = s2;
    red[tg][2][ci] = s3; red[tg][3][ci] = s4;
    __syncthreads();

    if (threadIdx.x < 4 * CT) {
        const int m = threadIdx.x >> 5, c = threadIdx.x & (CT - 1);
        float acc = 0.f;
        #pragma unroll
        for (int g = 0; g < NTG; ++g) acc += red[g][m][c];
        mom[m][c] = acc;
    }
    __syncthreads();

    // ---- Finalize: one lane per channel row ----
    if (threadIdx.x < CT) {
        const int c = threadIdx.x;
        const float n  = (float)TT;
        const float t1 = mom[0][c], t2 = mom[1][c], t3 = mom[2][c], t4 = mom[3][c];
        const float mu  = t1 / n;
        const float ex2 = t2 / n, ex3 = t3 / n, ex4 = t4 / n;
        float var = (t2 - n * mu * mu) / (n - 1.f);
        var = fmaxf(var, 0.f);
        const float sig  = fmaxf(sqrtf(var), 1e-4f);
        const float inv  = 1.f / sig;
        const float mu2  = mu * mu;
        const float ez3  = ex3 - 3.f * mu * ex2 + 2.f * mu * mu2;
        const float ez4  = ex4 - 4.f * mu * ex3 + 6.f * mu2 * ex2 - 3.f * mu2 * mu2;
        const float inv2 = inv * inv;
        const float skew  = ez3 * inv2 * inv;
        const float ekurt = ez4 * inv2 * inv2 - 3.f;

        float hid[HIDN];
        #pragma unroll
        for (int h = 0; h < HIDN; ++h) {
            float v = fmaf(W1[2*h], skew, fmaf(W1[2*h+1], ekurt, b1[h]));
            hid[h] = fmaxf(v, 0.f);
        }

        float e[KNOTS], kxr[KNOTS+1], kyr[KNOTS+1], dr[KNOTS+1];
        {   // widths -> kx
            float mx = -1e30f;
            #pragma unroll
            for (int o = 0; o < KNOTS; ++o) {
                float acc = b2[o];
                #pragma unroll
                for (int h = 0; h < HIDN; ++h) acc = fmaf(W2[o*HIDN + h], hid[h], acc);
                e[o] = acc; mx = fmaxf(mx, acc);
            }
            float sum = 0.f;
            #pragma unroll
            for (int o = 0; o < KNOTS; ++o) { e[o] = expf(e[o] - mx); sum += e[o]; }
            const float scale = (2.f * BOUNDF) / sum;
            float cum = -BOUNDF; kxr[0] = -BOUNDF;
            #pragma unroll
            for (int o = 0; o < KNOTS; ++o) { cum = fmaf(e[o], scale, cum); kxr[o+1] = cum; }
        }
        {   // heights -> ky
            float mx = -1e30f;
            #pragma unroll
            for (int o = 0; o < KNOTS; ++o) {
                float acc = b2[KNOTS + o];
                #pragma unroll
                for (int h = 0; h < HIDN; ++h) acc = fmaf(W2[(KNOTS+o)*HIDN + h], hid[h], acc);
                e[o] = acc; mx = fmaxf(mx, acc);
            }
            float sum = 0.f;
            #pragma unroll
            for (int o = 0; o < KNOTS; ++o) { e[o] = expf(e[o] - mx); sum += e[o]; }
            const float scale = (2.f * BOUNDF) / sum;
            float cum = -BOUNDF; kyr[0] = -BOUNDF;
            #pragma unroll
            for (int o = 0; o < KNOTS; ++o) { cum = fmaf(e[o], scale, cum); kyr[o+1] = cum; }
        }
        #pragma unroll
        for (int o = 0; o < KNOTS+1; ++o) {  // derivs = softplus + 1e-3
            float acc = b2[2*KNOTS + o];
            #pragma unroll
            for (int h = 0; h < HIDN; ++h) acc = fmaf(W2[(2*KNOTS+o)*HIDN + h], hid[h], acc);
            float sp = fmaxf(acc, 0.f) + log1pf(expf(-fabsf(acc)));
            dr[o] = sp + 1e-3f;
        }

        pA[c] = inv;
        pB[c] = -mu * inv;
        #pragma unroll
        for (int j = 1; j <= 7; ++j) pKx[j-1][c] = kxr[j];
        #pragma unroll
        for (int j = 0; j < KNOTS; ++j) {
            const float w    = kxr[j+1] - kxr[j];
            const float wm   = fmaxf(w, 1e-8f);
            const float invw = 1.f / wm;
            const float h    = kyr[j+1] - kyr[j];
            float4 A;
            A.x = -kxr[j] * invw;       // zeta = fma(z, invw, A.x)
            A.y = invw;
            F32H p; p.h.x = (_Float16)kyr[j]; p.h.y = (_Float16)h;
            F32H q; q.h.x = (_Float16)dr[j];  q.h.y = (_Float16)(dr[j] + dr[j+1]);
            A.z = p.f;  A.w = q.f;
            bins[j * CT + c] = A;
        }
    }
    __syncthreads();

    // ---- Phase 2: re-read slice in REVERSE t order, apply spline ----
    const float a  = pA[ci];
    const float bz = pB[ci];
    const float kx1 = pKx[0][ci], kx2 = pKx[1][ci], kx3 = pKx[2][ci],
                kx4 = pKx[3][ci], kx5 = pKx[4][ci], kx6 = pKx[5][ci],
                kx7 = pKx[6][ci];
    float* pot = out + base + (size_t)tg * CC;

    for (int kb = TPT / 8 - 1; kb >= 0; --kb) {   // 31..0 (reverse)
        float xv[8];
        #pragma unroll
        for (int j = 0; j < 8; ++j)
            xv[j] = pxt[(size_t)(kb * 8 + j) * (NTG * CC)];
        #pragma unroll
        for (int j = 0; j < 8; ++j) {
            const float z = fmaf(xv[j], a, bz);
            // binary bin search over interior knots kx1..kx7
            const bool  c4 = z >= kx4;
            const float mB = c4 ? kx6 : kx2;
            const bool  cB = z >= mB;
            const float nLo = c4 ? kx5 : kx1;
            const float nHi = c4 ? kx7 : kx3;
            const float mC = cB ? nHi : nLo;
            const bool  cC = z >= mC;
            const int off = (c4 ? 4*CT : 0) + (cB ? 2*CT : 0) + (cC ? CT : 0) + ci;
            const float4 A = bins[off];

            const float zeta = fmaf(z, A.y, A.x);
            const float u    = fmaf(-zeta, zeta, zeta);      // zeta*(1-zeta)
            F32H p; p.f = A.z;
            F32H q; q.f = A.w;
            const float kyl = (float)p.h.x;
            const float h   = (float)p.h.y;
            const float d0  = (float)q.h.x;
            const float D01 = (float)q.h.y;                  // d0 + d1
            const float s   = h * A.y;                       // h * invw
            const float R   = fmaf(-2.f, s, D01);            // d0+d1-2s
            const float den = fmaf(R, u, s);
            const float inner = fmaf(s * zeta, zeta, d0 * u);
            const float res = fmaf(h * inner,
                                   __builtin_amdgcn_rcpf(fmaxf(den, 1e-8f)), kyl);
            const float o = (fabsf(z) > BOUNDF) ? z : res;
            __builtin_nontemporal_store(o, &pot[(size_t)(kb * 8 + j) * (NTG * CC)]);
        }
    }
}

extern "C" void kernel_launch(void* const* d_in, const int* in_sizes, int n_in,
                              void* d_out, int out_size, void* d_ws, size_t ws_size,
                              hipStream_t stream) {
    const float* x  = (const float*)d_in[0];
    const float* W1 = (const float*)d_in[1];
    const float* b1 = (const float*)d_in[2];
    const float* W2 = (const float*)d_in[3];
    const float* b2 = (const float*)d_in[4];
    float* out = (float*)d_out;

    k_fused<<<dim3(CC / CT, NB), dim3(512), 0, stream>>>(x, W1, b1, W2, b2, out);
}

// Round 6
// 128.769 us; speedup vs baseline: 1.1359x; 1.0026x over previous
//
#include <hip/hip_runtime.h>
#include <math.h>

#define KNOTS 8
#define HIDN 32
#define TT 4096
#define CC 512
#define NB 32
#define BOUNDF 5.0f
#define CT 32          // channels per block
#define NTG 16         // t-groups (threads striding over T)
#define TPT (TT / NTG) // 256 elements per thread

// One block = one (batch, 32-channel) slice, 512 threads.
// Phase 1: moments over T. Finalize: 32 lanes -> spline params in LDS as three
//          float2 arrays (2-way bank aliasing only = free).
// Phase 2: re-read own 0.5 MB slice in REVERSE t order (L3-hot), apply spline,
//          nontemporal stores.
__global__ __launch_bounds__(512, 4)
void k_fused(const float* __restrict__ x, const float* __restrict__ W1,
             const float* __restrict__ b1, const float* __restrict__ W2,
             const float* __restrict__ b2, float* __restrict__ out)
{
    const int bb = blockIdx.y;               // 0..31
    const int c0 = blockIdx.x * CT;          // 0,32,...,480
    const int ci = threadIdx.x & (CT - 1);   // 0..31
    const int tg = threadIdx.x >> 5;         // 0..15

    __shared__ float red[NTG][4][CT];
    __shared__ float mom[4][CT];
    __shared__ float pA[CT], pB[CT];
    __shared__ float pKx[7][CT];
    __shared__ float2 bZ[KNOTS][CT];   // (-kxl*invw, invw)
    __shared__ float2 bY[KNOTS][CT];   // (kyl, h)
    __shared__ float2 bD[KNOTS][CT];   // (d0, d0+d1)

    const size_t base = (size_t)bb * TT * CC + c0 + ci;
    const float* pxt = x + base + (size_t)tg * CC;

    // ---- Phase 1: raw moments (each thread: 256 elements, stride 16 in t) ----
    float s1 = 0.f, s2 = 0.f, s3 = 0.f, s4 = 0.f;
    #pragma unroll 8
    for (int k = 0; k < TPT; ++k) {
        float v  = pxt[(size_t)k * (NTG * CC)];
        float v2 = v * v;
        s1 += v;
        s2 = fmaf(v,  v,  s2);
        s3 = fmaf(v2, v,  s3);
        s4 = fmaf(v2, v2, s4);
    }
    red[tg][0][ci] = s1; red[tg][1][ci] = s2;
    red[tg][2][ci] = s3; red[tg][3][ci] = s4;
    __syncthreads();

    if (threadIdx.x < 4 * CT) {
        const int m = threadIdx.x >> 5, c = threadIdx.x & (CT - 1);
        float acc = 0.f;
        #pragma unroll
        for (int g = 0; g < NTG; ++g) acc += red[g][m][c];
        mom[m][c] = acc;
    }
    __syncthreads();

    // ---- Finalize: one lane per channel row ----
    if (threadIdx.x < CT) {
        const int c = threadIdx.x;
        const float n  = (float)TT;
        const float t1 = mom[0][c], t2 = mom[1][c], t3 = mom[2][c], t4 = mom[3][c];
        const float mu  = t1 / n;
        const float ex2 = t2 / n, ex3 = t3 / n, ex4 = t4 / n;
        float var = (t2 - n * mu * mu) / (n - 1.f);
        var = fmaxf(var, 0.f);
        const float sig  = fmaxf(sqrtf(var), 1e-4f);
        const float inv  = 1.f / sig;
        const float mu2  = mu * mu;
        const float ez3  = ex3 - 3.f * mu * ex2 + 2.f * mu * mu2;
        const float ez4  = ex4 - 4.f * mu * ex3 + 6.f * mu2 * ex2 - 3.f * mu2 * mu2;
        const float inv2 = inv * inv;
        const float skew  = ez3 * inv2 * inv;
        const float ekurt = ez4 * inv2 * inv2 - 3.f;

        float hid[HIDN];
        #pragma unroll
        for (int h = 0; h < HIDN; ++h) {
            float v = fmaf(W1[2*h], skew, fmaf(W1[2*h+1], ekurt, b1[h]));
            hid[h] = fmaxf(v, 0.f);
        }

        float e[KNOTS], kxr[KNOTS+1], kyr[KNOTS+1], dr[KNOTS+1];
        {   // widths -> kx
            float mx = -1e30f;
            #pragma unroll
            for (int o = 0; o < KNOTS; ++o) {
                float acc = b2[o];
                #pragma unroll
                for (int h = 0; h < HIDN; ++h) acc = fmaf(W2[o*HIDN + h], hid[h], acc);
                e[o] = acc; mx = fmaxf(mx, acc);
            }
            float sum = 0.f;
            #pragma unroll
            for (int o = 0; o < KNOTS; ++o) { e[o] = expf(e[o] - mx); sum += e[o]; }
            const float scale = (2.f * BOUNDF) / sum;
            float cum = -BOUNDF; kxr[0] = -BOUNDF;
            #pragma unroll
            for (int o = 0; o < KNOTS; ++o) { cum = fmaf(e[o], scale, cum); kxr[o+1] = cum; }
        }
        {   // heights -> ky
            float mx = -1e30f;
            #pragma unroll
            for (int o = 0; o < KNOTS; ++o) {
                float acc = b2[KNOTS + o];
                #pragma unroll
                for (int h = 0; h < HIDN; ++h) acc = fmaf(W2[(KNOTS+o)*HIDN + h], hid[h], acc);
                e[o] = acc; mx = fmaxf(mx, acc);
            }
            float sum = 0.f;
            #pragma unroll
            for (int o = 0; o < KNOTS; ++o) { e[o] = expf(e[o] - mx); sum += e[o]; }
            const float scale = (2.f * BOUNDF) / sum;
            float cum = -BOUNDF; kyr[0] = -BOUNDF;
            #pragma unroll
            for (int o = 0; o < KNOTS; ++o) { cum = fmaf(e[o], scale, cum); kyr[o+1] = cum; }
        }
        #pragma unroll
        for (int o = 0; o < KNOTS+1; ++o) {  // derivs = softplus + 1e-3
            float acc = b2[2*KNOTS + o];
            #pragma unroll
            for (int h = 0; h < HIDN; ++h) acc = fmaf(W2[(2*KNOTS+o)*HIDN + h], hid[h], acc);
            float sp = fmaxf(acc, 0.f) + log1pf(expf(-fabsf(acc)));
            dr[o] = sp + 1e-3f;
        }

        pA[c] = inv;
        pB[c] = -mu * inv;
        #pragma unroll
        for (int j = 1; j <= 7; ++j) pKx[j-1][c] = kxr[j];
        #pragma unroll
        for (int j = 0; j < KNOTS; ++j) {
            const float w    = kxr[j+1] - kxr[j];
            const float wm   = fmaxf(w, 1e-8f);
            const float invw = 1.f / wm;
            const float h    = kyr[j+1] - kyr[j];
            bZ[j][c] = make_float2(-kxr[j] * invw, invw);
            bY[j][c] = make_float2(kyr[j], h);
            bD[j][c] = make_float2(dr[j], dr[j] + dr[j+1]);
        }
    }
    __syncthreads();

    // ---- Phase 2: re-read slice in REVERSE t order, apply spline ----
    const float a  = pA[ci];
    const float bz = pB[ci];
    const float kx1 = pKx[0][ci], kx2 = pKx[1][ci], kx3 = pKx[2][ci],
                kx4 = pKx[3][ci], kx5 = pKx[4][ci], kx6 = pKx[5][ci],
                kx7 = pKx[6][ci];
    float* pot = out + base + (size_t)tg * CC;

    for (int kb = TPT / 8 - 1; kb >= 0; --kb) {   // 31..0 (reverse)
        float xv[8];
        #pragma unroll
        for (int j = 0; j < 8; ++j)
            xv[j] = pxt[(size_t)(kb * 8 + j) * (NTG * CC)];
        #pragma unroll
        for (int j = 0; j < 8; ++j) {
            const float z = fmaf(xv[j], a, bz);
            // binary bin search over interior knots kx1..kx7
            const bool  c4 = z >= kx4;
            const float mB = c4 ? kx6 : kx2;
            const bool  cB = z >= mB;
            const float nLo = c4 ? kx5 : kx1;
            const float nHi = c4 ? kx7 : kx3;
            const float mC = cB ? nHi : nLo;
            const bool  cC = z >= mC;
            const int off = (c4 ? 4*CT : 0) + (cB ? 2*CT : 0) + (cC ? CT : 0) + ci;

            const float2 Z = ((const float2*)bZ)[off];
            const float2 Y = ((const float2*)bY)[off];
            const float2 D = ((const float2*)bD)[off];

            const float zeta = fmaf(z, Z.y, Z.x);
            const float u    = fmaf(-zeta, zeta, zeta);      // zeta*(1-zeta)
            const float s    = Y.y * Z.y;                    // h * invw
            const float R    = fmaf(-2.f, s, D.y);           // d0+d1-2s
            const float den  = fmaf(R, u, s);
            const float inner= fmaf(s * zeta, zeta, D.x * u);
            const float res  = fmaf(Y.y * inner,
                                    __builtin_amdgcn_rcpf(fmaxf(den, 1e-8f)), Y.x);
            const float o = (fabsf(z) > BOUNDF) ? z : res;
            __builtin_nontemporal_store(o, &pot[(size_t)(kb * 8 + j) * (NTG * CC)]);
        }
    }
}

extern "C" void kernel_launch(void* const* d_in, const int* in_sizes, int n_in,
                              void* d_out, int out_size, void* d_ws, size_t ws_size,
                              hipStream_t stream) {
    const float* x  = (const float*)d_in[0];
    const float* W1 = (const float*)d_in[1];
    const float* b1 = (const float*)d_in[2];
    const float* W2 = (const float*)d_in[3];
    const float* b2 = (const float*)d_in[4];
    float* out = (float*)d_out;

    k_fused<<<dim3(CC / CT, NB), dim3(512), 0, stream>>>(x, W1, b1, W2, b2, out);
}